// Round 6
// baseline (123.708 us; speedup 1.0000x reference)
//
#include <hip/hip_runtime.h>

// Problem constants (from reference): x:[8192,64,32] f32, weight:[10,2048] f32
// out[b,c] = logsumexp_d(x[b,d] + log_softmax(weight)[c,d])
//          = log( sum_d exp(x[b,d]) * softmax(weight)[c,d] )
constexpr int B = 8192;
constexpr int D = 2048;   // P*N = 64*32
constexpr int C = 10;

// ---------------- Kernel 1: p[c,:] = softmax(weight[c,:]) ----------------
__global__ __launch_bounds__(256) void softmax_w_kernel(
    const float* __restrict__ w, float* __restrict__ p) {
  const int c = blockIdx.x;
  const int t = threadIdx.x;          // 0..255
  const int lane = t & 63, wid = t >> 6;

  const float4* wr = reinterpret_cast<const float4*>(w + c * D);
  float4 v0 = wr[t];          // d = 4t .. 4t+3
  float4 v1 = wr[t + 256];    // d = 1024 + 4t ..

  // block max
  float m = fmaxf(fmaxf(fmaxf(v0.x, v0.y), fmaxf(v0.z, v0.w)),
                  fmaxf(fmaxf(v1.x, v1.y), fmaxf(v1.z, v1.w)));
#pragma unroll
  for (int o = 1; o < 64; o <<= 1) m = fmaxf(m, __shfl_xor(m, o));
  __shared__ float sred[4];
  if (lane == 0) sred[wid] = m;
  __syncthreads();
  m = fmaxf(fmaxf(sred[0], sred[1]), fmaxf(sred[2], sred[3]));
  __syncthreads();  // sred reused below

  float4 e0, e1;
  e0.x = __expf(v0.x - m); e0.y = __expf(v0.y - m);
  e0.z = __expf(v0.z - m); e0.w = __expf(v0.w - m);
  e1.x = __expf(v1.x - m); e1.y = __expf(v1.y - m);
  e1.z = __expf(v1.z - m); e1.w = __expf(v1.w - m);

  float s = (e0.x + e0.y + e0.z + e0.w) + (e1.x + e1.y + e1.z + e1.w);
#pragma unroll
  for (int o = 1; o < 64; o <<= 1) s += __shfl_xor(s, o);
  if (lane == 0) sred[wid] = s;
  __syncthreads();
  s = (sred[0] + sred[1]) + (sred[2] + sred[3]);

  const float inv = 1.0f / s;
  float4 q0 = {e0.x * inv, e0.y * inv, e0.z * inv, e0.w * inv};
  float4 q1 = {e1.x * inv, e1.y * inv, e1.z * inv, e1.w * inv};
  float4* pr = reinterpret_cast<float4*>(p + c * D);
  pr[t] = q0;
  pr[t + 256] = q1;
}

// ---------------- Kernel 2: out[b,c] = log( exp(x[b,:]) . p[c,:] ) ----------------
// Block = 256 threads = 4 waves; each wave handles R=4 consecutive rows.
// Lane's data: float4 index f4 = j*64 + lane, j = 0..7  (covers D/4 = 512 float4s)
__global__ __launch_bounds__(256) void lse_main_kernel(
    const float* __restrict__ x, const float* __restrict__ p,
    float* __restrict__ out) {
  const int t = threadIdx.x;
  const int lane = t & 63, wid = t >> 6;
  const int row0 = blockIdx.x * 16 + wid * 4;   // 4 rows per wave

  const float4* xr = reinterpret_cast<const float4*>(x + (size_t)row0 * D);
  constexpr int D4 = D / 4;  // 512

  float acc[4][C];
#pragma unroll
  for (int r = 0; r < 4; ++r)
#pragma unroll
    for (int c = 0; c < C; ++c) acc[r][c] = 0.0f;

#pragma unroll
  for (int j = 0; j < 8; ++j) {
    const int f4 = j * 64 + lane;

    float4 xv[4];
#pragma unroll
    for (int r = 0; r < 4; ++r) xv[r] = xr[r * D4 + f4];

    float4 e[4];
#pragma unroll
    for (int r = 0; r < 4; ++r) {
      e[r].x = __expf(xv[r].x);
      e[r].y = __expf(xv[r].y);
      e[r].z = __expf(xv[r].z);
      e[r].w = __expf(xv[r].w);
    }

#pragma unroll
    for (int c = 0; c < C; ++c) {
      const float4 pv = reinterpret_cast<const float4*>(p + c * D)[f4];
#pragma unroll
      for (int r = 0; r < 4; ++r) {
        acc[r][c] += e[r].x * pv.x + e[r].y * pv.y +
                     e[r].z * pv.z + e[r].w * pv.w;
      }
    }
  }

  // wave butterfly reduction + store (precise logf in epilogue — cost is nil)
#pragma unroll
  for (int r = 0; r < 4; ++r) {
#pragma unroll
    for (int c = 0; c < C; ++c) {
      float v = acc[r][c];
#pragma unroll
      for (int o = 1; o < 64; o <<= 1) v += __shfl_xor(v, o);
      if (lane == c) out[(size_t)(row0 + r) * C + c] = logf(v);
    }
  }
}

extern "C" void kernel_launch(void* const* d_in, const int* in_sizes, int n_in,
                              void* d_out, int out_size, void* d_ws, size_t ws_size,
                              hipStream_t stream) {
  const float* x = (const float*)d_in[0];       // [B, D]
  const float* w = (const float*)d_in[1];       // [C, D]
  float* out = (float*)d_out;                   // [B, C]
  float* p = (float*)d_ws;                      // [C, D] scratch (80 KB)

  softmax_w_kernel<<<C, 256, 0, stream>>>(w, p);
  lse_main_kernel<<<B / 16, 256, 0, stream>>>(x, p, out);
}